// Round 1
// baseline (1382.693 us; speedup 1.0000x reference)
//
#include <hip/hip_runtime.h>
#include <math.h>

#define EPS 1e-5f
#define BATCH 32
#define LAYERS 6
#define FDIM 2048

// h layout: [b][3072] flat, element (s,n,e) at b*3072 + s*96 + n*3 + e
// (pure reshape of x's (b,c,h,w) layout, matching the reference)

__global__ void conv_residual_kernel(const float* __restrict__ x,
                                     const float* __restrict__ conv_w,
                                     const float* __restrict__ conv_b,
                                     float* __restrict__ h) {
    int b = blockIdx.x / 3, ch = blockIdx.x % 3;
    const float* xb = x + (size_t)(b * 3 + ch) * 1024;
    const float* wc = conv_w + (size_t)ch * 1024;
    int tid = threadIdx.x;
    float s = 0.f;
#pragma unroll
    for (int i = 0; i < 4; ++i) {
        int idx = tid + i * 256;
        s += xb[idx] * wc[idx];
    }
#pragma unroll
    for (int m = 32; m >= 1; m >>= 1) s += __shfl_down(s, m);
    __shared__ float red[4];
    int wave = tid >> 6, lane = tid & 63;
    if (lane == 0) red[wave] = s;
    __syncthreads();
    if (tid == 0) red[0] = red[0] + red[1] + red[2] + red[3] + conv_b[ch];
    __syncthreads();
    float c = red[0];
    float* hb = h + (size_t)(b * 3 + ch) * 1024;
#pragma unroll
    for (int i = 0; i < 4; ++i) {
        int idx = tid + i * 256;
        hb[idx] = xb[idx] + c;
    }
}

// wpack[l][k] = {w1_0, w1_1, w1_2, b1}, {w2_0, w2_1, w2_2, 0}
__global__ void pack_kernel(const float* __restrict__ W1, const float* __restrict__ b1,
                            const float* __restrict__ W2, float* __restrict__ wpack) {
    int idx = blockIdx.x * 256 + threadIdx.x;  // l*2048 + k
    if (idx >= LAYERS * FDIM) return;
    int l = idx / FDIM, k = idx % FDIM;
    float4 a, w;
    const float* w1 = W1 + (size_t)l * FDIM * 3 + (size_t)k * 3;
    a.x = w1[0]; a.y = w1[1]; a.z = w1[2];
    a.w = b1[(size_t)l * FDIM + k];
    const float* w2 = W2 + (size_t)l * 3 * FDIM + k;
    w.x = w2[0]; w.y = w2[FDIM]; w.z = w2[2 * FDIM]; w.w = 0.f;
    float4* wp = (float4*)wpack;
    wp[idx * 2 + 0] = a;
    wp[idx * 2 + 1] = w;
}

__global__ void attn_ln1_kernel(float* __restrict__ h,
                                const float* __restrict__ Wqkv,
                                const float* __restrict__ bqkv,
                                const float* __restrict__ Wo,
                                const float* __restrict__ bo,
                                const float* __restrict__ ln1_g,
                                const float* __restrict__ ln1_b,
                                int l) {
    int b = blockIdx.x >> 2;       // 32 batches x 4 n-groups
    int ngrp = blockIdx.x & 3;
    int s = threadIdx.x & 31;
    int nl = threadIdx.x >> 5;     // 0..7
    int n = ngrp * 8 + nl;

    const float* wq = Wqkv + l * 27;
    const float* bq = bqkv + l * 9;

    float* hp = h + (size_t)b * 3072 + s * 96 + n * 3;
    float h0 = hp[0], h1 = hp[1], h2 = hp[2];

    float q[3], kk[3], vv[3];
#pragma unroll
    for (int f = 0; f < 3; ++f) {
        q[f]  = fmaf(wq[f*3+0], h0, fmaf(wq[f*3+1], h1, fmaf(wq[f*3+2], h2, bq[f])));
        kk[f] = fmaf(wq[9+f*3+0], h0, fmaf(wq[9+f*3+1], h1, fmaf(wq[9+f*3+2], h2, bq[3+f])));
        vv[f] = fmaf(wq[18+f*3+0], h0, fmaf(wq[18+f*3+1], h1, fmaf(wq[18+f*3+2], h2, bq[6+f])));
    }
    __shared__ float kbuf[8][3][33], vbuf[8][3][33];
#pragma unroll
    for (int e = 0; e < 3; ++e) { kbuf[nl][e][s] = kk[e]; vbuf[nl][e][s] = vv[e]; }
    __syncthreads();

    float oatt[3];
#pragma unroll
    for (int e = 0; e < 3; ++e) {
        float qv = q[e];
        float m = -1e30f;
#pragma unroll
        for (int t = 0; t < 32; ++t) m = fmaxf(m, qv * kbuf[nl][e][t]);
        float sum = 0.f, acc = 0.f;
#pragma unroll
        for (int t = 0; t < 32; ++t) {
            float p = __expf(qv * kbuf[nl][e][t] - m);
            sum += p;
            acc = fmaf(p, vbuf[nl][e][t], acc);
        }
        oatt[e] = acc / sum;
    }
    const float* wo = Wo + l * 9;
    float x0 = h0 + fmaf(wo[0], oatt[0], fmaf(wo[1], oatt[1], fmaf(wo[2], oatt[2], bo[l*3+0])));
    float x1 = h1 + fmaf(wo[3], oatt[0], fmaf(wo[4], oatt[1], fmaf(wo[5], oatt[2], bo[l*3+1])));
    float x2 = h2 + fmaf(wo[6], oatt[0], fmaf(wo[7], oatt[1], fmaf(wo[8], oatt[2], bo[l*3+2])));
    float mu = (x0 + x1 + x2) * (1.f / 3.f);
    float d0 = x0 - mu, d1 = x1 - mu, d2 = x2 - mu;
    float var = (d0 * d0 + d1 * d1 + d2 * d2) * (1.f / 3.f);
    float inv = 1.0f / sqrtf(var + EPS);
    hp[0] = d0 * inv * ln1_g[l*3+0] + ln1_b[l*3+0];
    hp[1] = d1 * inv * ln1_g[l*3+1] + ln1_b[l*3+1];
    hp[2] = d2 * inv * ln1_g[l*3+2] + ln1_b[l*3+2];
}

// 8 lanes per position split the 2048 hidden units; shfl reduce; lane g==0 does LN2.
__global__ void mlp_ln2_kernel(float* __restrict__ h,
                               const float* __restrict__ wpack,
                               const float* __restrict__ b2,
                               const float* __restrict__ ln2_g,
                               const float* __restrict__ ln2_b,
                               int l) {
    int tid = threadIdx.x;
    int g = tid & 7;
    int pos = blockIdx.x * 32 + (tid >> 3);
    float* hp = h + (size_t)pos * 3;
    float h0 = hp[0], h1 = hp[1], h2 = hp[2];

    const float4* wp = (const float4*)wpack + ((size_t)l * FDIM + g * 256) * 2;
    float p0 = 0.f, p1 = 0.f, p2 = 0.f;
#pragma unroll 4
    for (int k = 0; k < 256; ++k) {
        float4 a = wp[k * 2 + 0];
        float4 w = wp[k * 2 + 1];
        float t = fmaf(a.x, h0, fmaf(a.y, h1, fmaf(a.z, h2, a.w)));
        float gl = 0.5f * t * (1.0f + erff(t * 0.70710678118654752f));
        p0 = fmaf(gl, w.x, p0);
        p1 = fmaf(gl, w.y, p1);
        p2 = fmaf(gl, w.z, p2);
    }
#pragma unroll
    for (int m = 1; m < 8; m <<= 1) {
        p0 += __shfl_xor(p0, m);
        p1 += __shfl_xor(p1, m);
        p2 += __shfl_xor(p2, m);
    }
    if (g == 0) {
        float x0 = h0 + p0 + b2[l*3+0];
        float x1 = h1 + p1 + b2[l*3+1];
        float x2 = h2 + p2 + b2[l*3+2];
        float mu = (x0 + x1 + x2) * (1.f / 3.f);
        float d0 = x0 - mu, d1 = x1 - mu, d2 = x2 - mu;
        float var = (d0 * d0 + d1 * d1 + d2 * d2) * (1.f / 3.f);
        float inv = 1.0f / sqrtf(var + EPS);
        hp[0] = d0 * inv * ln2_g[l*3+0] + ln2_b[l*3+0];
        hp[1] = d1 * inv * ln2_g[l*3+1] + ln2_b[l*3+1];
        hp[2] = d2 * inv * ln2_g[l*3+2] + ln2_b[l*3+2];
    }
}

__global__ void head_kernel(const float* __restrict__ h,
                            const float* __restrict__ mlp_W,
                            const float* __restrict__ mlp_b,
                            float* __restrict__ out) {
    int b = blockIdx.x, tid = threadIdx.x;
    float hh[12];
#pragma unroll
    for (int m = 0; m < 12; ++m) hh[m] = h[(size_t)b * 3072 + tid + m * 256];
    float p[10];
#pragma unroll
    for (int j = 0; j < 10; ++j) {
        const float* wj = mlp_W + (size_t)j * 3072;
        float s = 0.f;
#pragma unroll
        for (int m = 0; m < 12; ++m) s = fmaf(hh[m], wj[tid + m * 256], s);
#pragma unroll
        for (int d = 32; d >= 1; d >>= 1) s += __shfl_down(s, d);
        p[j] = s;
    }
    __shared__ float red[10][4];
    int wave = tid >> 6, lane = tid & 63;
    if (lane == 0) {
#pragma unroll
        for (int j = 0; j < 10; ++j) red[j][wave] = p[j];
    }
    __syncthreads();
    if (tid < 10)
        out[b * 10 + tid] = red[tid][0] + red[tid][1] + red[tid][2] + red[tid][3] + mlp_b[tid];
}

extern "C" void kernel_launch(void* const* d_in, const int* in_sizes, int n_in,
                              void* d_out, int out_size, void* d_ws, size_t ws_size,
                              hipStream_t stream) {
    const float* x      = (const float*)d_in[0];
    const float* conv_w = (const float*)d_in[1];
    const float* conv_b = (const float*)d_in[2];
    const float* Wqkv   = (const float*)d_in[3];
    const float* bqkv   = (const float*)d_in[4];
    const float* Wo     = (const float*)d_in[5];
    const float* bo     = (const float*)d_in[6];
    const float* W1     = (const float*)d_in[7];
    const float* b1     = (const float*)d_in[8];
    const float* W2     = (const float*)d_in[9];
    const float* b2     = (const float*)d_in[10];
    const float* ln1_g  = (const float*)d_in[11];
    const float* ln1_b  = (const float*)d_in[12];
    const float* ln2_g  = (const float*)d_in[13];
    const float* ln2_b  = (const float*)d_in[14];
    const float* mlp_W  = (const float*)d_in[15];
    const float* mlp_b  = (const float*)d_in[16];
    float* out = (float*)d_out;

    float* h     = (float*)d_ws;   // 98304 floats
    float* wpack = h + 98304;      // 98304 floats (16B-aligned: 393216 bytes offset)

    hipLaunchKernelGGL(conv_residual_kernel, dim3(96), dim3(256), 0, stream,
                       x, conv_w, conv_b, h);
    hipLaunchKernelGGL(pack_kernel, dim3(48), dim3(256), 0, stream, W1, b1, W2, wpack);
    for (int l = 0; l < LAYERS; ++l) {
        hipLaunchKernelGGL(attn_ln1_kernel, dim3(128), dim3(256), 0, stream,
                           h, Wqkv, bqkv, Wo, bo, ln1_g, ln1_b, l);
        hipLaunchKernelGGL(mlp_ln2_kernel, dim3(1024), dim3(256), 0, stream,
                           h, wpack, b2, ln2_g, ln2_b, l);
    }
    hipLaunchKernelGGL(head_kernel, dim3(32), dim3(256), 0, stream, h, mlp_W, mlp_b, out);
}

// Round 2
// 420.735 us; speedup vs baseline: 3.2864x; 3.2864x over previous
//
#include <hip/hip_runtime.h>
#include <math.h>

#define EPS 1e-5f
#define BATCH 32
#define LAYERS 6
#define FDIM 2048

// h layout: [b][3072] flat, element (s,n,e) at b*3072 + s*96 + n*3 + e
// (pure reshape of x's (b,c,h,w) layout, matching the reference)

__global__ void conv_residual_kernel(const float* __restrict__ x,
                                     const float* __restrict__ conv_w,
                                     const float* __restrict__ conv_b,
                                     float* __restrict__ h) {
    int b = blockIdx.x / 3, ch = blockIdx.x % 3;
    const float* xb = x + (size_t)(b * 3 + ch) * 1024;
    const float* wc = conv_w + (size_t)ch * 1024;
    int tid = threadIdx.x;
    float s = 0.f;
#pragma unroll
    for (int i = 0; i < 4; ++i) {
        int idx = tid + i * 256;
        s += xb[idx] * wc[idx];
    }
#pragma unroll
    for (int m = 32; m >= 1; m >>= 1) s += __shfl_down(s, m);
    __shared__ float red[4];
    int wave = tid >> 6, lane = tid & 63;
    if (lane == 0) red[wave] = s;
    __syncthreads();
    if (tid == 0) red[0] = red[0] + red[1] + red[2] + red[3] + conv_b[ch];
    __syncthreads();
    float c = red[0];
    float* hb = h + (size_t)(b * 3 + ch) * 1024;
#pragma unroll
    for (int i = 0; i < 4; ++i) {
        int idx = tid + i * 256;
        hb[idx] = xb[idx] + c;
    }
}

// wpack[l][k] = {w1_0, w1_1, w1_2, b1}, {w2_0, w2_1, w2_2, 0}
__global__ void pack_kernel(const float* __restrict__ W1, const float* __restrict__ b1,
                            const float* __restrict__ W2, float* __restrict__ wpack) {
    int idx = blockIdx.x * 256 + threadIdx.x;  // l*2048 + k
    if (idx >= LAYERS * FDIM) return;
    int l = idx / FDIM, k = idx % FDIM;
    float4 a, w;
    const float* w1 = W1 + (size_t)l * FDIM * 3 + (size_t)k * 3;
    a.x = w1[0]; a.y = w1[1]; a.z = w1[2];
    a.w = b1[(size_t)l * FDIM + k];
    const float* w2 = W2 + (size_t)l * 3 * FDIM + k;
    w.x = w2[0]; w.y = w2[FDIM]; w.z = w2[2 * FDIM]; w.w = 0.f;
    float4* wp = (float4*)wpack;
    wp[idx * 2 + 0] = a;
    wp[idx * 2 + 1] = w;
}

__global__ void attn_ln1_kernel(float* __restrict__ h,
                                const float* __restrict__ Wqkv,
                                const float* __restrict__ bqkv,
                                const float* __restrict__ Wo,
                                const float* __restrict__ bo,
                                const float* __restrict__ ln1_g,
                                const float* __restrict__ ln1_b,
                                int l) {
    int b = blockIdx.x >> 2;       // 32 batches x 4 n-groups
    int ngrp = blockIdx.x & 3;
    int s = threadIdx.x & 31;
    int nl = threadIdx.x >> 5;     // 0..7
    int n = ngrp * 8 + nl;

    const float* wq = Wqkv + l * 27;
    const float* bq = bqkv + l * 9;

    float* hp = h + (size_t)b * 3072 + s * 96 + n * 3;
    float h0 = hp[0], h1 = hp[1], h2 = hp[2];

    float q[3], kk[3], vv[3];
#pragma unroll
    for (int f = 0; f < 3; ++f) {
        q[f]  = fmaf(wq[f*3+0], h0, fmaf(wq[f*3+1], h1, fmaf(wq[f*3+2], h2, bq[f])));
        kk[f] = fmaf(wq[9+f*3+0], h0, fmaf(wq[9+f*3+1], h1, fmaf(wq[9+f*3+2], h2, bq[3+f])));
        vv[f] = fmaf(wq[18+f*3+0], h0, fmaf(wq[18+f*3+1], h1, fmaf(wq[18+f*3+2], h2, bq[6+f])));
    }
    __shared__ float kbuf[8][3][33], vbuf[8][3][33];
#pragma unroll
    for (int e = 0; e < 3; ++e) { kbuf[nl][e][s] = kk[e]; vbuf[nl][e][s] = vv[e]; }
    __syncthreads();

    float oatt[3];
#pragma unroll
    for (int e = 0; e < 3; ++e) {
        float qv = q[e];
        float m = -1e30f;
#pragma unroll
        for (int t = 0; t < 32; ++t) m = fmaxf(m, qv * kbuf[nl][e][t]);
        float sum = 0.f, acc = 0.f;
#pragma unroll
        for (int t = 0; t < 32; ++t) {
            float p = __expf(qv * kbuf[nl][e][t] - m);
            sum += p;
            acc = fmaf(p, vbuf[nl][e][t], acc);
        }
        oatt[e] = acc / sum;
    }
    const float* wo = Wo + l * 9;
    float x0 = h0 + fmaf(wo[0], oatt[0], fmaf(wo[1], oatt[1], fmaf(wo[2], oatt[2], bo[l*3+0])));
    float x1 = h1 + fmaf(wo[3], oatt[0], fmaf(wo[4], oatt[1], fmaf(wo[5], oatt[2], bo[l*3+1])));
    float x2 = h2 + fmaf(wo[6], oatt[0], fmaf(wo[7], oatt[1], fmaf(wo[8], oatt[2], bo[l*3+2])));
    float mu = (x0 + x1 + x2) * (1.f / 3.f);
    float d0 = x0 - mu, d1 = x1 - mu, d2 = x2 - mu;
    float var = (d0 * d0 + d1 * d1 + d2 * d2) * (1.f / 3.f);
    float inv = 1.0f / sqrtf(var + EPS);
    hp[0] = d0 * inv * ln1_g[l*3+0] + ln1_b[l*3+0];
    hp[1] = d1 * inv * ln1_g[l*3+1] + ln1_b[l*3+1];
    hp[2] = d2 * inv * ln1_g[l*3+2] + ln1_b[l*3+2];
}

// 32 lanes per position, k strided by 32 (coalesced); shfl_xor reduce; lane g==0 does LN2.
__global__ void mlp_ln2_kernel(float* __restrict__ h,
                               const float* __restrict__ wpack,
                               const float* __restrict__ b2,
                               const float* __restrict__ ln2_g,
                               const float* __restrict__ ln2_b,
                               int l) {
    int tid = threadIdx.x;
    int g = tid & 31;
    int pos = blockIdx.x * 8 + (tid >> 5);
    float* hp = h + (size_t)pos * 3;
    float h0 = hp[0], h1 = hp[1], h2 = hp[2];

    const float4* wp = (const float4*)wpack + (size_t)l * FDIM * 2;
    float p0 = 0.f, p1 = 0.f, p2 = 0.f;
#pragma unroll 4
    for (int i = 0; i < 64; ++i) {
        int k = i * 32 + g;
        float4 a = wp[k * 2 + 0];
        float4 w = wp[k * 2 + 1];
        float t = fmaf(a.x, h0, fmaf(a.y, h1, fmaf(a.z, h2, a.w)));
        float gl = 0.5f * t * (1.0f + erff(t * 0.70710678118654752f));
        p0 = fmaf(gl, w.x, p0);
        p1 = fmaf(gl, w.y, p1);
        p2 = fmaf(gl, w.z, p2);
    }
#pragma unroll
    for (int m = 1; m < 32; m <<= 1) {
        p0 += __shfl_xor(p0, m);
        p1 += __shfl_xor(p1, m);
        p2 += __shfl_xor(p2, m);
    }
    if (g == 0) {
        float x0 = h0 + p0 + b2[l*3+0];
        float x1 = h1 + p1 + b2[l*3+1];
        float x2 = h2 + p2 + b2[l*3+2];
        float mu = (x0 + x1 + x2) * (1.f / 3.f);
        float d0 = x0 - mu, d1 = x1 - mu, d2 = x2 - mu;
        float var = (d0 * d0 + d1 * d1 + d2 * d2) * (1.f / 3.f);
        float inv = 1.0f / sqrtf(var + EPS);
        hp[0] = d0 * inv * ln2_g[l*3+0] + ln2_b[l*3+0];
        hp[1] = d1 * inv * ln2_g[l*3+1] + ln2_b[l*3+1];
        hp[2] = d2 * inv * ln2_g[l*3+2] + ln2_b[l*3+2];
    }
}

__global__ void head_kernel(const float* __restrict__ h,
                            const float* __restrict__ mlp_W,
                            const float* __restrict__ mlp_b,
                            float* __restrict__ out) {
    int b = blockIdx.x, tid = threadIdx.x;
    float hh[12];
#pragma unroll
    for (int m = 0; m < 12; ++m) hh[m] = h[(size_t)b * 3072 + tid + m * 256];
    float p[10];
#pragma unroll
    for (int j = 0; j < 10; ++j) {
        const float* wj = mlp_W + (size_t)j * 3072;
        float s = 0.f;
#pragma unroll
        for (int m = 0; m < 12; ++m) s = fmaf(hh[m], wj[tid + m * 256], s);
#pragma unroll
        for (int d = 32; d >= 1; d >>= 1) s += __shfl_down(s, d);
        p[j] = s;
    }
    __shared__ float red[10][4];
    int wave = tid >> 6, lane = tid & 63;
    if (lane == 0) {
#pragma unroll
        for (int j = 0; j < 10; ++j) red[j][wave] = p[j];
    }
    __syncthreads();
    if (tid < 10)
        out[b * 10 + tid] = red[tid][0] + red[tid][1] + red[tid][2] + red[tid][3] + mlp_b[tid];
}

extern "C" void kernel_launch(void* const* d_in, const int* in_sizes, int n_in,
                              void* d_out, int out_size, void* d_ws, size_t ws_size,
                              hipStream_t stream) {
    const float* x      = (const float*)d_in[0];
    const float* conv_w = (const float*)d_in[1];
    const float* conv_b = (const float*)d_in[2];
    const float* Wqkv   = (const float*)d_in[3];
    const float* bqkv   = (const float*)d_in[4];
    const float* Wo     = (const float*)d_in[5];
    const float* bo     = (const float*)d_in[6];
    const float* W1     = (const float*)d_in[7];
    const float* b1     = (const float*)d_in[8];
    const float* W2     = (const float*)d_in[9];
    const float* b2     = (const float*)d_in[10];
    const float* ln1_g  = (const float*)d_in[11];
    const float* ln1_b  = (const float*)d_in[12];
    const float* ln2_g  = (const float*)d_in[13];
    const float* ln2_b  = (const float*)d_in[14];
    const float* mlp_W  = (const float*)d_in[15];
    const float* mlp_b  = (const float*)d_in[16];
    float* out = (float*)d_out;

    float* h     = (float*)d_ws;   // 98304 floats
    float* wpack = h + 98304;      // 98304 floats (16B-aligned: 393216 bytes offset)

    hipLaunchKernelGGL(conv_residual_kernel, dim3(96), dim3(256), 0, stream,
                       x, conv_w, conv_b, h);
    hipLaunchKernelGGL(pack_kernel, dim3(48), dim3(256), 0, stream, W1, b1, W2, wpack);
    for (int l = 0; l < LAYERS; ++l) {
        hipLaunchKernelGGL(attn_ln1_kernel, dim3(128), dim3(256), 0, stream,
                           h, Wqkv, bqkv, Wo, bo, ln1_g, ln1_b, l);
        hipLaunchKernelGGL(mlp_ln2_kernel, dim3(4096), dim3(256), 0, stream,
                           h, wpack, b2, ln2_g, ln2_b, l);
    }
    hipLaunchKernelGGL(head_kernel, dim3(32), dim3(256), 0, stream, h, mlp_W, mlp_b, out);
}

// Round 3
// 288.328 us; speedup vs baseline: 4.7955x; 1.4592x over previous
//
#include <hip/hip_runtime.h>
#include <math.h>

#define EPS 1e-5f
#define BATCH 32
#define LAYERS 6
#define FDIM 2048

// h layout: [b][3072] flat, element (s,n,e) at b*3072 + s*96 + n*3 + e
// (pure reshape of x's (b,c,h,w) layout, matching the reference)

__global__ void conv_residual_kernel(const float* __restrict__ x,
                                     const float* __restrict__ conv_w,
                                     const float* __restrict__ conv_b,
                                     float* __restrict__ h) {
    int b = blockIdx.x / 3, ch = blockIdx.x % 3;
    const float* xb = x + (size_t)(b * 3 + ch) * 1024;
    const float* wc = conv_w + (size_t)ch * 1024;
    int tid = threadIdx.x;
    float s = 0.f;
#pragma unroll
    for (int i = 0; i < 4; ++i) {
        int idx = tid + i * 256;
        s += xb[idx] * wc[idx];
    }
#pragma unroll
    for (int m = 32; m >= 1; m >>= 1) s += __shfl_down(s, m);
    __shared__ float red[4];
    int wave = tid >> 6, lane = tid & 63;
    if (lane == 0) red[wave] = s;
    __syncthreads();
    if (tid == 0) red[0] = red[0] + red[1] + red[2] + red[3] + conv_b[ch];
    __syncthreads();
    float c = red[0];
    float* hb = h + (size_t)(b * 3 + ch) * 1024;
#pragma unroll
    for (int i = 0; i < 4; ++i) {
        int idx = tid + i * 256;
        hb[idx] = xb[idx] + c;
    }
}

// wpack[l][k] = {w1_0, w1_1, w1_2, b1}, {w2_0, w2_1, w2_2, 0}
__global__ void pack_kernel(const float* __restrict__ W1, const float* __restrict__ b1,
                            const float* __restrict__ W2, float* __restrict__ wpack) {
    int idx = blockIdx.x * 256 + threadIdx.x;  // l*2048 + k
    if (idx >= LAYERS * FDIM) return;
    int l = idx / FDIM, k = idx % FDIM;
    float4 a, w;
    const float* w1 = W1 + (size_t)l * FDIM * 3 + (size_t)k * 3;
    a.x = w1[0]; a.y = w1[1]; a.z = w1[2];
    a.w = b1[(size_t)l * FDIM + k];
    const float* w2 = W2 + (size_t)l * 3 * FDIM + k;
    w.x = w2[0]; w.y = w2[FDIM]; w.z = w2[2 * FDIM]; w.w = 0.f;
    float4* wp = (float4*)wpack;
    wp[idx * 2 + 0] = a;
    wp[idx * 2 + 1] = w;
}

__global__ void attn_ln1_kernel(float* __restrict__ h,
                                const float* __restrict__ Wqkv,
                                const float* __restrict__ bqkv,
                                const float* __restrict__ Wo,
                                const float* __restrict__ bo,
                                const float* __restrict__ ln1_g,
                                const float* __restrict__ ln1_b,
                                int l) {
    int b = blockIdx.x >> 2;       // 32 batches x 4 n-groups
    int ngrp = blockIdx.x & 3;
    int s = threadIdx.x & 31;
    int nl = threadIdx.x >> 5;     // 0..7
    int n = ngrp * 8 + nl;

    const float* wq = Wqkv + l * 27;
    const float* bq = bqkv + l * 9;

    float* hp = h + (size_t)b * 3072 + s * 96 + n * 3;
    float h0 = hp[0], h1 = hp[1], h2 = hp[2];

    float q[3], kk[3], vv[3];
#pragma unroll
    for (int f = 0; f < 3; ++f) {
        q[f]  = fmaf(wq[f*3+0], h0, fmaf(wq[f*3+1], h1, fmaf(wq[f*3+2], h2, bq[f])));
        kk[f] = fmaf(wq[9+f*3+0], h0, fmaf(wq[9+f*3+1], h1, fmaf(wq[9+f*3+2], h2, bq[3+f])));
        vv[f] = fmaf(wq[18+f*3+0], h0, fmaf(wq[18+f*3+1], h1, fmaf(wq[18+f*3+2], h2, bq[6+f])));
    }
    __shared__ float kbuf[8][3][33], vbuf[8][3][33];
#pragma unroll
    for (int e = 0; e < 3; ++e) { kbuf[nl][e][s] = kk[e]; vbuf[nl][e][s] = vv[e]; }
    __syncthreads();

    float oatt[3];
#pragma unroll
    for (int e = 0; e < 3; ++e) {
        float qv = q[e];
        float m = -1e30f;
#pragma unroll
        for (int t = 0; t < 32; ++t) m = fmaxf(m, qv * kbuf[nl][e][t]);
        float sum = 0.f, acc = 0.f;
#pragma unroll
        for (int t = 0; t < 32; ++t) {
            float p = __expf(qv * kbuf[nl][e][t] - m);
            sum += p;
            acc = fmaf(p, vbuf[nl][e][t], acc);
        }
        oatt[e] = acc / sum;
    }
    const float* wo = Wo + l * 9;
    float x0 = h0 + fmaf(wo[0], oatt[0], fmaf(wo[1], oatt[1], fmaf(wo[2], oatt[2], bo[l*3+0])));
    float x1 = h1 + fmaf(wo[3], oatt[0], fmaf(wo[4], oatt[1], fmaf(wo[5], oatt[2], bo[l*3+1])));
    float x2 = h2 + fmaf(wo[6], oatt[0], fmaf(wo[7], oatt[1], fmaf(wo[8], oatt[2], bo[l*3+2])));
    float mu = (x0 + x1 + x2) * (1.f / 3.f);
    float d0 = x0 - mu, d1 = x1 - mu, d2 = x2 - mu;
    float var = (d0 * d0 + d1 * d1 + d2 * d2) * (1.f / 3.f);
    float inv = 1.0f / sqrtf(var + EPS);
    hp[0] = d0 * inv * ln1_g[l*3+0] + ln1_b[l*3+0];
    hp[1] = d1 * inv * ln1_g[l*3+1] + ln1_b[l*3+1];
    hp[2] = d2 * inv * ln1_g[l*3+2] + ln1_b[l*3+2];
}

// One wave handles 4 positions; lane l walks k = 64*i + l (no duplicate loads).
// gelu via Abramowitz-Stegun 7.1.26 erf (|err|<=1.5e-7), branchless:
//   gl = relu(t) - 0.5*|t| * poly(1/(1+p*|t|/sqrt2)) * exp(-t^2/2)
__global__ void mlp_ln2_kernel(float* __restrict__ h,
                               const float* __restrict__ wpack,
                               const float* __restrict__ b2,
                               const float* __restrict__ ln2_g,
                               const float* __restrict__ ln2_b,
                               int l) {
    int tid = threadIdx.x;
    int lane = tid & 63;
    int wv = tid >> 6;                       // 0..3
    int pos0 = blockIdx.x * 16 + wv * 4;     // 4 consecutive positions per wave
    float* hbase = h + (size_t)pos0 * 3;
    const float4* hq = (const float4*)hbase; // 12 contiguous floats, 16B aligned
    float4 hA = hq[0], hB = hq[1], hC = hq[2];
    float hx[4][3] = {{hA.x, hA.y, hA.z},
                      {hA.w, hB.x, hB.y},
                      {hB.z, hB.w, hC.x},
                      {hC.y, hC.z, hC.w}};
    float acc[4][3] = {{0.f,0.f,0.f},{0.f,0.f,0.f},{0.f,0.f,0.f},{0.f,0.f,0.f}};

    const float4* wp = (const float4*)wpack + (size_t)l * FDIM * 2 + (size_t)lane * 2;
#pragma unroll 2
    for (int i = 0; i < 32; ++i) {
        float4 a = wp[i * 128 + 0];          // k = i*64+lane
        float4 w = wp[i * 128 + 1];
#pragma unroll
        for (int p = 0; p < 4; ++p) {
            float t  = fmaf(a.x, hx[p][0], fmaf(a.y, hx[p][1], fmaf(a.z, hx[p][2], a.w)));
            float e  = __expf(-0.5f * t * t);
            float at = fabsf(t);
            float wr = __builtin_amdgcn_rcpf(fmaf(0.23164194f, at, 1.0f)); // 1/(1+p*t/sqrt2)
            float poly = fmaf(fmaf(fmaf(fmaf(1.061405429f, wr, -1.453152027f),
                                        wr, 1.421413741f),
                                   wr, -0.284496736f),
                              wr, 0.254829592f) * wr;
            float gl = fmaf(-0.5f * at, poly * e, fmaxf(t, 0.f));
            acc[p][0] = fmaf(gl, w.x, acc[p][0]);
            acc[p][1] = fmaf(gl, w.y, acc[p][1]);
            acc[p][2] = fmaf(gl, w.z, acc[p][2]);
        }
    }
#pragma unroll
    for (int m = 1; m < 64; m <<= 1) {
#pragma unroll
        for (int p = 0; p < 4; ++p) {
            acc[p][0] += __shfl_xor(acc[p][0], m);
            acc[p][1] += __shfl_xor(acc[p][1], m);
            acc[p][2] += __shfl_xor(acc[p][2], m);
        }
    }
    if (lane == 0) {
        float o[12];
#pragma unroll
        for (int p = 0; p < 4; ++p) {
            float x0 = hx[p][0] + acc[p][0] + b2[l*3+0];
            float x1 = hx[p][1] + acc[p][1] + b2[l*3+1];
            float x2 = hx[p][2] + acc[p][2] + b2[l*3+2];
            float mu = (x0 + x1 + x2) * (1.f / 3.f);
            float d0 = x0 - mu, d1 = x1 - mu, d2 = x2 - mu;
            float var = (d0 * d0 + d1 * d1 + d2 * d2) * (1.f / 3.f);
            float inv = 1.0f / sqrtf(var + EPS);
            o[p*3+0] = d0 * inv * ln2_g[l*3+0] + ln2_b[l*3+0];
            o[p*3+1] = d1 * inv * ln2_g[l*3+1] + ln2_b[l*3+1];
            o[p*3+2] = d2 * inv * ln2_g[l*3+2] + ln2_b[l*3+2];
        }
        float4* ho = (float4*)hbase;
        ho[0] = make_float4(o[0], o[1], o[2], o[3]);
        ho[1] = make_float4(o[4], o[5], o[6], o[7]);
        ho[2] = make_float4(o[8], o[9], o[10], o[11]);
    }
}

__global__ void head_kernel(const float* __restrict__ h,
                            const float* __restrict__ mlp_W,
                            const float* __restrict__ mlp_b,
                            float* __restrict__ out) {
    int b = blockIdx.x, tid = threadIdx.x;
    float hh[12];
#pragma unroll
    for (int m = 0; m < 12; ++m) hh[m] = h[(size_t)b * 3072 + tid + m * 256];
    float p[10];
#pragma unroll
    for (int j = 0; j < 10; ++j) {
        const float* wj = mlp_W + (size_t)j * 3072;
        float s = 0.f;
#pragma unroll
        for (int m = 0; m < 12; ++m) s = fmaf(hh[m], wj[tid + m * 256], s);
#pragma unroll
        for (int d = 32; d >= 1; d >>= 1) s += __shfl_down(s, d);
        p[j] = s;
    }
    __shared__ float red[10][4];
    int wave = tid >> 6, lane = tid & 63;
    if (lane == 0) {
#pragma unroll
        for (int j = 0; j < 10; ++j) red[j][wave] = p[j];
    }
    __syncthreads();
    if (tid < 10)
        out[b * 10 + tid] = red[tid][0] + red[tid][1] + red[tid][2] + red[tid][3] + mlp_b[tid];
}

extern "C" void kernel_launch(void* const* d_in, const int* in_sizes, int n_in,
                              void* d_out, int out_size, void* d_ws, size_t ws_size,
                              hipStream_t stream) {
    const float* x      = (const float*)d_in[0];
    const float* conv_w = (const float*)d_in[1];
    const float* conv_b = (const float*)d_in[2];
    const float* Wqkv   = (const float*)d_in[3];
    const float* bqkv   = (const float*)d_in[4];
    const float* Wo     = (const float*)d_in[5];
    const float* bo     = (const float*)d_in[6];
    const float* W1     = (const float*)d_in[7];
    const float* b1     = (const float*)d_in[8];
    const float* W2     = (const float*)d_in[9];
    const float* b2     = (const float*)d_in[10];
    const float* ln1_g  = (const float*)d_in[11];
    const float* ln1_b  = (const float*)d_in[12];
    const float* ln2_g  = (const float*)d_in[13];
    const float* ln2_b  = (const float*)d_in[14];
    const float* mlp_W  = (const float*)d_in[15];
    const float* mlp_b  = (const float*)d_in[16];
    float* out = (float*)d_out;

    float* h     = (float*)d_ws;   // 98304 floats
    float* wpack = h + 98304;      // 98304 floats (16B-aligned: 393216 bytes offset)

    hipLaunchKernelGGL(conv_residual_kernel, dim3(96), dim3(256), 0, stream,
                       x, conv_w, conv_b, h);
    hipLaunchKernelGGL(pack_kernel, dim3(48), dim3(256), 0, stream, W1, b1, W2, wpack);
    for (int l = 0; l < LAYERS; ++l) {
        hipLaunchKernelGGL(attn_ln1_kernel, dim3(128), dim3(256), 0, stream,
                           h, Wqkv, bqkv, Wo, bo, ln1_g, ln1_b, l);
        hipLaunchKernelGGL(mlp_ln2_kernel, dim3(2048), dim3(256), 0, stream,
                           h, wpack, b2, ln2_g, ln2_b, l);
    }
    hipLaunchKernelGGL(head_kernel, dim3(32), dim3(256), 0, stream, h, mlp_W, mlp_b, out);
}

// Round 4
// 52.425 us; speedup vs baseline: 26.3747x; 5.4998x over previous
//
#include <hip/hip_runtime.h>
#include <math.h>

#define EPS 1e-5f
#define LAYERS 6
#define FDIM 2048
#define NTAB 1024

// h layout: [b][3072] flat, element (s,n,e) at b*3072 + s*96 + n*3 + e

__global__ void conv_residual_kernel(const float* __restrict__ x,
                                     const float* __restrict__ conv_w,
                                     const float* __restrict__ conv_b,
                                     float* __restrict__ h) {
    int b = blockIdx.x / 3, ch = blockIdx.x % 3;
    const float* xb = x + (size_t)(b * 3 + ch) * 1024;
    const float* wc = conv_w + (size_t)ch * 1024;
    int tid = threadIdx.x;
    float s = 0.f;
#pragma unroll
    for (int i = 0; i < 4; ++i) {
        int idx = tid + i * 256;
        s += xb[idx] * wc[idx];
    }
#pragma unroll
    for (int m = 32; m >= 1; m >>= 1) s += __shfl_down(s, m);
    __shared__ float red[4];
    int wave = tid >> 6, lane = tid & 63;
    if (lane == 0) red[wave] = s;
    __syncthreads();
    if (tid == 0) red[0] = red[0] + red[1] + red[2] + red[3] + conv_b[ch];
    __syncthreads();
    float c = red[0];
    float* hb = h + (size_t)(b * 3 + ch) * 1024;
#pragma unroll
    for (int i = 0; i < 4; ++i) {
        int idx = tid + i * 256;
        hb[idx] = xb[idx] + c;
    }
}

__device__ __forceinline__ float gelu_as(float t) {
    // A&S 7.1.26 erf, branchless: gl = relu(t) - 0.5*|t|*poly*exp(-t^2/2)
    float e  = __expf(-0.5f * t * t);
    float at = fabsf(t);
    float wr = __builtin_amdgcn_rcpf(fmaf(0.23164194f, at, 1.0f));
    float poly = fmaf(fmaf(fmaf(fmaf(1.061405429f, wr, -1.453152027f),
                                wr, 1.421413741f),
                           wr, -0.284496736f),
                      wr, 0.254829592f) * wr;
    return fmaf(-0.5f * at, poly * e, fmaxf(t, 0.f));
}

// Build tab[l][j] = MLP_acc( hn(theta_j) ), hn = ln1_g * z(theta) + ln1_b,
// z on the radius-sqrt(3) circle in the plane z0+z1+z2=0.
// Slot j <-> diamond coordinate d = j*(4/NTAB).
__global__ void tab_kernel(const float* __restrict__ W1, const float* __restrict__ b1,
                           const float* __restrict__ W2,
                           const float* __restrict__ ln1_g, const float* __restrict__ ln1_b,
                           float4* __restrict__ tab) {
    int wv = threadIdx.x >> 6, lane = threadIdx.x & 63;
    int l = blockIdx.x >> 6;                     // 64 blocks per layer
    int jbase = (blockIdx.x & 63) * 16 + wv * 4; // 4 entries per wave

    float g0 = ln1_g[l*3+0], g1 = ln1_g[l*3+1], g2 = ln1_g[l*3+2];
    float bb0 = ln1_b[l*3+0], bb1 = ln1_b[l*3+1], bb2 = ln1_b[l*3+2];

    float hx[4][3];
#pragma unroll
    for (int p = 0; p < 4; ++p) {
        float d = (float)(jbase + p) * (4.0f / NTAB);
        float cn = (d <= 2.0f) ? 1.0f - d : d - 3.0f;
        float asn = 1.0f - fabsf(cn);
        float sn = (d <= 2.0f) ? asn : -asn;
        float inv = 1.0f / sqrtf(cn * cn + sn * sn);
        float c = cn * inv, s = sn * inv;
        float z0 = fmaf(1.2247449f, c, 0.70710678f * s);
        float z1 = fmaf(-1.2247449f, c, 0.70710678f * s);
        float z2 = -1.4142136f * s;
        hx[p][0] = fmaf(g0, z0, bb0);
        hx[p][1] = fmaf(g1, z1, bb1);
        hx[p][2] = fmaf(g2, z2, bb2);
    }
    float acc[4][3] = {{0.f,0.f,0.f},{0.f,0.f,0.f},{0.f,0.f,0.f},{0.f,0.f,0.f}};

    const float* w1p = W1 + (size_t)l * FDIM * 3;
    const float* b1p = b1 + (size_t)l * FDIM;
    const float* w2p = W2 + (size_t)l * 3 * FDIM;
#pragma unroll 2
    for (int i = 0; i < 32; ++i) {
        int k = i * 64 + lane;
        float a0 = w1p[k*3+0], a1 = w1p[k*3+1], a2 = w1p[k*3+2], ab = b1p[k];
        float w0 = w2p[k], w1v = w2p[FDIM + k], w2v = w2p[2*FDIM + k];
#pragma unroll
        for (int p = 0; p < 4; ++p) {
            float t = fmaf(a0, hx[p][0], fmaf(a1, hx[p][1], fmaf(a2, hx[p][2], ab)));
            float gl = gelu_as(t);
            acc[p][0] = fmaf(gl, w0,  acc[p][0]);
            acc[p][1] = fmaf(gl, w1v, acc[p][1]);
            acc[p][2] = fmaf(gl, w2v, acc[p][2]);
        }
    }
#pragma unroll
    for (int m = 1; m < 64; m <<= 1) {
#pragma unroll
        for (int p = 0; p < 4; ++p) {
            acc[p][0] += __shfl_xor(acc[p][0], m);
            acc[p][1] += __shfl_xor(acc[p][1], m);
            acc[p][2] += __shfl_xor(acc[p][2], m);
        }
    }
    if (lane == 0) {
#pragma unroll
        for (int p = 0; p < 4; ++p)
            tab[(size_t)l * NTAB + jbase + p] = make_float4(acc[p][0], acc[p][1], acc[p][2], 0.f);
    }
}

// All 6 layers fused. Block = (batch b, group of 8 n's) x 32 s = 256 threads.
// h lives in registers; attention mixes only within the block.
__global__ __launch_bounds__(256) void layers6_kernel(
        float* __restrict__ h,
        const float* __restrict__ Wqkv, const float* __restrict__ bqkv,
        const float* __restrict__ Wo,   const float* __restrict__ bo,
        const float* __restrict__ ln1_g, const float* __restrict__ ln1_b,
        const float* __restrict__ b2v,
        const float* __restrict__ ln2_g, const float* __restrict__ ln2_b,
        const float4* __restrict__ tab) {
    int b = blockIdx.x >> 2, ngrp = blockIdx.x & 3;
    int s = threadIdx.x & 31, nl = threadIdx.x >> 5;
    int n = ngrp * 8 + nl;
    __shared__ float kbuf[8][3][32], vbuf[8][3][32];

    float* hp = h + (size_t)b * 3072 + s * 96 + n * 3;
    float h0 = hp[0], h1 = hp[1], h2 = hp[2];

    for (int l = 0; l < LAYERS; ++l) {
        const float* wq = Wqkv + l * 27;
        const float* bq = bqkv + l * 9;
        float q[3], kk[3], vv[3];
#pragma unroll
        for (int f = 0; f < 3; ++f) {
            q[f]  = fmaf(wq[f*3+0], h0, fmaf(wq[f*3+1], h1, fmaf(wq[f*3+2], h2, bq[f])));
            kk[f] = fmaf(wq[9+f*3+0], h0, fmaf(wq[9+f*3+1], h1, fmaf(wq[9+f*3+2], h2, bq[3+f])));
            vv[f] = fmaf(wq[18+f*3+0], h0, fmaf(wq[18+f*3+1], h1, fmaf(wq[18+f*3+2], h2, bq[6+f])));
        }
        __syncthreads();   // previous layer's kbuf reads complete
#pragma unroll
        for (int e = 0; e < 3; ++e) { kbuf[nl][e][s] = kk[e]; vbuf[nl][e][s] = vv[e]; }
        __syncthreads();

        float oatt[3];
#pragma unroll
        for (int e = 0; e < 3; ++e) {
            float a = q[e] * 1.44269504f;   // exp2 base; no max-sub (|q*k| bounded)
            float sum = 0.f, acc = 0.f;
#pragma unroll
            for (int t = 0; t < 32; ++t) {
                float p = exp2f(a * kbuf[nl][e][t]);
                sum += p;
                acc = fmaf(p, vbuf[nl][e][t], acc);
            }
            oatt[e] = acc / sum;
        }
        const float* wo = Wo + l * 9;
        float x0 = h0 + fmaf(wo[0], oatt[0], fmaf(wo[1], oatt[1], fmaf(wo[2], oatt[2], bo[l*3+0])));
        float x1 = h1 + fmaf(wo[3], oatt[0], fmaf(wo[4], oatt[1], fmaf(wo[5], oatt[2], bo[l*3+1])));
        float x2 = h2 + fmaf(wo[6], oatt[0], fmaf(wo[7], oatt[1], fmaf(wo[8], oatt[2], bo[l*3+2])));
        // ln1 -> z (pre-gain), hn (post-gain)
        float mu = (x0 + x1 + x2) * (1.f/3.f);
        float d0 = x0 - mu, d1 = x1 - mu, d2 = x2 - mu;
        float var = (d0*d0 + d1*d1 + d2*d2) * (1.f/3.f);
        float inv = 1.0f / sqrtf(var + EPS);
        float z0 = d0 * inv, z1 = d1 * inv, z2 = d2 * inv;
        float hn0 = fmaf(z0, ln1_g[l*3+0], ln1_b[l*3+0]);
        float hn1 = fmaf(z1, ln1_g[l*3+1], ln1_b[l*3+1]);
        float hn2 = fmaf(z2, ln1_g[l*3+2], ln1_b[l*3+2]);
        // MLP via 1-D manifold table: diamond coordinate of z
        float cc = 0.40824829f * (z0 - z1);
        float ss = 0.23570226f * (z0 + z1 - 2.f * z2);
        float m  = fabsf(cc) + fabsf(ss) + 1e-30f;
        float cnn = cc * __builtin_amdgcn_rcpf(m);
        float dq = (ss >= 0.f) ? (1.f - cnn) : (3.f + cnn);
        float xq = dq * (float)(NTAB / 4);
        float fl = floorf(xq);
        float fr = xq - fl;
        int j0 = ((int)fl) & (NTAB - 1);
        int j1 = (j0 + 1) & (NTAB - 1);
        float4 ta = tab[(size_t)l * NTAB + j0];
        float4 tb = tab[(size_t)l * NTAB + j1];
        float f0 = fmaf(fr, tb.x - ta.x, ta.x);
        float f1 = fmaf(fr, tb.y - ta.y, ta.y);
        float f2 = fmaf(fr, tb.z - ta.z, ta.z);
        // residual + ln2
        float y0 = hn0 + f0 + b2v[l*3+0];
        float y1 = hn1 + f1 + b2v[l*3+1];
        float y2 = hn2 + f2 + b2v[l*3+2];
        float mu2 = (y0 + y1 + y2) * (1.f/3.f);
        float e0 = y0 - mu2, e1 = y1 - mu2, e2 = y2 - mu2;
        float var2 = (e0*e0 + e1*e1 + e2*e2) * (1.f/3.f);
        float inv2 = 1.0f / sqrtf(var2 + EPS);
        h0 = fmaf(e0 * inv2, ln2_g[l*3+0], ln2_b[l*3+0]);
        h1 = fmaf(e1 * inv2, ln2_g[l*3+1], ln2_b[l*3+1]);
        h2 = fmaf(e2 * inv2, ln2_g[l*3+2], ln2_b[l*3+2]);
    }
    hp[0] = h0; hp[1] = h1; hp[2] = h2;
}

__global__ void head_kernel(const float* __restrict__ h,
                            const float* __restrict__ mlp_W,
                            const float* __restrict__ mlp_b,
                            float* __restrict__ out) {
    int b = blockIdx.x, tid = threadIdx.x;
    float hh[12];
#pragma unroll
    for (int m = 0; m < 12; ++m) hh[m] = h[(size_t)b * 3072 + tid + m * 256];
    float p[10];
#pragma unroll
    for (int j = 0; j < 10; ++j) {
        const float* wj = mlp_W + (size_t)j * 3072;
        float s = 0.f;
#pragma unroll
        for (int m = 0; m < 12; ++m) s = fmaf(hh[m], wj[tid + m * 256], s);
#pragma unroll
        for (int d = 32; d >= 1; d >>= 1) s += __shfl_down(s, d);
        p[j] = s;
    }
    __shared__ float red[10][4];
    int wave = tid >> 6, lane = tid & 63;
    if (lane == 0) {
#pragma unroll
        for (int j = 0; j < 10; ++j) red[j][wave] = p[j];
    }
    __syncthreads();
    if (tid < 10)
        out[b * 10 + tid] = red[tid][0] + red[tid][1] + red[tid][2] + red[tid][3] + mlp_b[tid];
}

extern "C" void kernel_launch(void* const* d_in, const int* in_sizes, int n_in,
                              void* d_out, int out_size, void* d_ws, size_t ws_size,
                              hipStream_t stream) {
    const float* x      = (const float*)d_in[0];
    const float* conv_w = (const float*)d_in[1];
    const float* conv_b = (const float*)d_in[2];
    const float* Wqkv   = (const float*)d_in[3];
    const float* bqkv   = (const float*)d_in[4];
    const float* Wo     = (const float*)d_in[5];
    const float* bo     = (const float*)d_in[6];
    const float* W1     = (const float*)d_in[7];
    const float* b1     = (const float*)d_in[8];
    const float* W2     = (const float*)d_in[9];
    const float* b2     = (const float*)d_in[10];
    const float* ln1_g  = (const float*)d_in[11];
    const float* ln1_b  = (const float*)d_in[12];
    const float* ln2_g  = (const float*)d_in[13];
    const float* ln2_b  = (const float*)d_in[14];
    const float* mlp_W  = (const float*)d_in[15];
    const float* mlp_b  = (const float*)d_in[16];
    float* out = (float*)d_out;

    float*  h   = (float*)d_ws;                        // 98304 floats (393216 B)
    float4* tab = (float4*)((char*)d_ws + 393216);     // 6*1024 float4 (196608 B)

    hipLaunchKernelGGL(conv_residual_kernel, dim3(96), dim3(256), 0, stream,
                       x, conv_w, conv_b, h);
    hipLaunchKernelGGL(tab_kernel, dim3(LAYERS * 64), dim3(256), 0, stream,
                       W1, b1, W2, ln1_g, ln1_b, tab);
    hipLaunchKernelGGL(layers6_kernel, dim3(128), dim3(256), 0, stream,
                       h, Wqkv, bqkv, Wo, bo, ln1_g, ln1_b, b2, ln2_g, ln2_b, tab);
    hipLaunchKernelGGL(head_kernel, dim3(32), dim3(256), 0, stream, h, mlp_W, mlp_b, out);
}

// Round 5
// 42.573 us; speedup vs baseline: 32.4779x; 1.2314x over previous
//
#include <hip/hip_runtime.h>
#include <math.h>

#define EPS 1e-5f
#define LAYERS 6
#define FDIM 2048
#define NTAB 512

// h layout: [b][3072] flat, element (s,n,e) at b*3072 + s*96 + n*3 + e

__device__ __forceinline__ float gelu_as(float t) {
    // A&S 7.1.26 erf, branchless: gl = relu(t) - 0.5*|t|*poly*exp(-t^2/2)
    float e  = __expf(-0.5f * t * t);
    float at = fabsf(t);
    float wr = __builtin_amdgcn_rcpf(fmaf(0.23164194f, at, 1.0f));
    float poly = fmaf(fmaf(fmaf(fmaf(1.061405429f, wr, -1.453152027f),
                                wr, 1.421413741f),
                           wr, -0.284496736f),
                      wr, 0.254829592f) * wr;
    return fmaf(-0.5f * at, poly * e, fmaxf(t, 0.f));
}

// tab[l][j] = MLP_acc( hn(theta_j) ), hn = ln1_g * z(theta_j) + ln1_b,
// z on the radius-sqrt(3) circle in the plane z0+z1+z2=0.
// Slot j <-> diamond coordinate d = j*(4/NTAB).
__global__ void tab_kernel(const float* __restrict__ W1, const float* __restrict__ b1,
                           const float* __restrict__ W2,
                           const float* __restrict__ ln1_g, const float* __restrict__ ln1_b,
                           float4* __restrict__ tab) {
    int wv = threadIdx.x >> 6, lane = threadIdx.x & 63;
    int l = blockIdx.x >> 5;                     // NTAB/16 = 32 blocks per layer
    int jbase = (blockIdx.x & 31) * 16 + wv * 4; // 4 entries per wave

    float g0 = ln1_g[l*3+0], g1 = ln1_g[l*3+1], g2 = ln1_g[l*3+2];
    float bb0 = ln1_b[l*3+0], bb1 = ln1_b[l*3+1], bb2 = ln1_b[l*3+2];

    float hx[4][3];
#pragma unroll
    for (int p = 0; p < 4; ++p) {
        float d = (float)(jbase + p) * (4.0f / NTAB);
        float cn = (d <= 2.0f) ? 1.0f - d : d - 3.0f;
        float asn = 1.0f - fabsf(cn);
        float sn = (d <= 2.0f) ? asn : -asn;
        float inv = 1.0f / sqrtf(cn * cn + sn * sn);
        float c = cn * inv, s = sn * inv;
        float z0 = fmaf(1.2247449f, c, 0.70710678f * s);
        float z1 = fmaf(-1.2247449f, c, 0.70710678f * s);
        float z2 = -1.4142136f * s;
        hx[p][0] = fmaf(g0, z0, bb0);
        hx[p][1] = fmaf(g1, z1, bb1);
        hx[p][2] = fmaf(g2, z2, bb2);
    }
    float acc[4][3] = {{0.f,0.f,0.f},{0.f,0.f,0.f},{0.f,0.f,0.f},{0.f,0.f,0.f}};

    const float* w1p = W1 + (size_t)l * FDIM * 3;
    const float* b1p = b1 + (size_t)l * FDIM;
    const float* w2p = W2 + (size_t)l * 3 * FDIM;
#pragma unroll 2
    for (int i = 0; i < 32; ++i) {
        int k = i * 64 + lane;
        float a0 = w1p[k*3+0], a1 = w1p[k*3+1], a2 = w1p[k*3+2], ab = b1p[k];
        float w0 = w2p[k], w1v = w2p[FDIM + k], w2v = w2p[2*FDIM + k];
#pragma unroll
        for (int p = 0; p < 4; ++p) {
            float t = fmaf(a0, hx[p][0], fmaf(a1, hx[p][1], fmaf(a2, hx[p][2], ab)));
            float gl = gelu_as(t);
            acc[p][0] = fmaf(gl, w0,  acc[p][0]);
            acc[p][1] = fmaf(gl, w1v, acc[p][1]);
            acc[p][2] = fmaf(gl, w2v, acc[p][2]);
        }
    }
#pragma unroll
    for (int m = 1; m < 64; m <<= 1) {
#pragma unroll
        for (int p = 0; p < 4; ++p) {
            acc[p][0] += __shfl_xor(acc[p][0], m);
            acc[p][1] += __shfl_xor(acc[p][1], m);
            acc[p][2] += __shfl_xor(acc[p][2], m);
        }
    }
    if (lane == 0) {
#pragma unroll
        for (int p = 0; p < 4; ++p)
            tab[(size_t)l * NTAB + jbase + p] = make_float4(acc[p][0], acc[p][1], acc[p][2], 0.f);
    }
}

// conv + all 6 layers fused. Block = one wave: (batch b, pair of n's) x 32 s.
// conv's three 1024-dot scalars are recomputed per block (cheap); h stays in
// registers across all layers; attention mixes only within the wave's 32 s.
__global__ __launch_bounds__(64) void fused6_kernel(
        const float* __restrict__ x,
        const float* __restrict__ conv_w, const float* __restrict__ conv_b,
        const float* __restrict__ Wqkv, const float* __restrict__ bqkv,
        const float* __restrict__ Wo,   const float* __restrict__ bo,
        const float* __restrict__ ln1_g, const float* __restrict__ ln1_b,
        const float* __restrict__ b2v,
        const float* __restrict__ ln2_g, const float* __restrict__ ln2_b,
        const float4* __restrict__ tab,
        float* __restrict__ h) {
    int b = blockIdx.x >> 4, ngrp = blockIdx.x & 15;
    int tid = threadIdx.x;
    int s = tid & 31, nl = tid >> 5;   // nl in {0,1}
    int n = ngrp * 2 + nl;
    __shared__ float kbuf[2][3][32], vbuf[2][3][32];

    // in-block conv: c[ch] = dot(x[b,ch,:,:], conv_w[ch]) + conv_b[ch]
    const float4* xb4 = (const float4*)(x + (size_t)b * 3072);
    const float4* cw4 = (const float4*)conv_w;
    float cs0 = 0.f, cs1 = 0.f, cs2 = 0.f;
#pragma unroll
    for (int i = 0; i < 4; ++i) {
        int f0 = i * 64 + tid;
        float4 xv = xb4[f0], wv = cw4[f0];
        cs0 = fmaf(xv.x, wv.x, fmaf(xv.y, wv.y, fmaf(xv.z, wv.z, fmaf(xv.w, wv.w, cs0))));
        float4 xv1 = xb4[f0 + 256], wv1 = cw4[f0 + 256];
        cs1 = fmaf(xv1.x, wv1.x, fmaf(xv1.y, wv1.y, fmaf(xv1.z, wv1.z, fmaf(xv1.w, wv1.w, cs1))));
        float4 xv2 = xb4[f0 + 512], wv2 = cw4[f0 + 512];
        cs2 = fmaf(xv2.x, wv2.x, fmaf(xv2.y, wv2.y, fmaf(xv2.z, wv2.z, fmaf(xv2.w, wv2.w, cs2))));
    }
#pragma unroll
    for (int m = 1; m < 64; m <<= 1) {
        cs0 += __shfl_xor(cs0, m);
        cs1 += __shfl_xor(cs1, m);
        cs2 += __shfl_xor(cs2, m);
    }
    float c0 = cs0 + conv_b[0], c1 = cs1 + conv_b[1], c2 = cs2 + conv_b[2];

    int flat = s * 96 + n * 3;
    const float* xb = x + (size_t)b * 3072 + flat;
    float h0 = xb[0] + ((flat     < 1024) ? c0 : (flat     < 2048 ? c1 : c2));
    float h1 = xb[1] + ((flat + 1 < 1024) ? c0 : (flat + 1 < 2048 ? c1 : c2));
    float h2 = xb[2] + ((flat + 2 < 1024) ? c0 : (flat + 2 < 2048 ? c1 : c2));

    for (int l = 0; l < LAYERS; ++l) {
        const float* wq = Wqkv + l * 27;
        const float* bq = bqkv + l * 9;
        float q[3], kk[3], vv[3];
#pragma unroll
        for (int f = 0; f < 3; ++f) {
            q[f]  = fmaf(wq[f*3+0], h0, fmaf(wq[f*3+1], h1, fmaf(wq[f*3+2], h2, bq[f])));
            kk[f] = fmaf(wq[9+f*3+0], h0, fmaf(wq[9+f*3+1], h1, fmaf(wq[9+f*3+2], h2, bq[3+f])));
            vv[f] = fmaf(wq[18+f*3+0], h0, fmaf(wq[18+f*3+1], h1, fmaf(wq[18+f*3+2], h2, bq[6+f])));
        }
        __syncthreads();   // single-wave block: near-free; orders kbuf reuse
#pragma unroll
        for (int e = 0; e < 3; ++e) { kbuf[nl][e][s] = kk[e]; vbuf[nl][e][s] = vv[e]; }
        __syncthreads();

        float oatt[3];
#pragma unroll
        for (int e = 0; e < 3; ++e) {
            float a = q[e] * 1.44269504f;   // exp2 base; no max-sub (|q*k| bounded)
            float sum = 0.f, acc = 0.f;
#pragma unroll
            for (int t = 0; t < 32; ++t) {
                float p = exp2f(a * kbuf[nl][e][t]);
                sum += p;
                acc = fmaf(p, vbuf[nl][e][t], acc);
            }
            oatt[e] = acc / sum;
        }
        const float* wo = Wo + l * 9;
        float x0 = h0 + fmaf(wo[0], oatt[0], fmaf(wo[1], oatt[1], fmaf(wo[2], oatt[2], bo[l*3+0])));
        float x1 = h1 + fmaf(wo[3], oatt[0], fmaf(wo[4], oatt[1], fmaf(wo[5], oatt[2], bo[l*3+1])));
        float x2 = h2 + fmaf(wo[6], oatt[0], fmaf(wo[7], oatt[1], fmaf(wo[8], oatt[2], bo[l*3+2])));
        // ln1 -> z (pre-gain), hn (post-gain)
        float mu = (x0 + x1 + x2) * (1.f/3.f);
        float d0 = x0 - mu, d1 = x1 - mu, d2 = x2 - mu;
        float var = (d0*d0 + d1*d1 + d2*d2) * (1.f/3.f);
        float inv = 1.0f / sqrtf(var + EPS);
        float z0 = d0 * inv, z1 = d1 * inv, z2 = d2 * inv;
        float hn0 = fmaf(z0, ln1_g[l*3+0], ln1_b[l*3+0]);
        float hn1 = fmaf(z1, ln1_g[l*3+1], ln1_b[l*3+1]);
        float hn2 = fmaf(z2, ln1_g[l*3+2], ln1_b[l*3+2]);
        // MLP via 1-D manifold table: diamond coordinate of z
        float cc = 0.40824829f * (z0 - z1);
        float ss = 0.23570226f * (z0 + z1 - 2.f * z2);
        float m  = fabsf(cc) + fabsf(ss) + 1e-30f;
        float cnn = cc * __builtin_amdgcn_rcpf(m);
        float dq = (ss >= 0.f) ? (1.f - cnn) : (3.f + cnn);
        float xq = dq * (float)(NTAB / 4);
        float fl = floorf(xq);
        float fr = xq - fl;
        int j0 = ((int)fl) & (NTAB - 1);
        int j1 = (j0 + 1) & (NTAB - 1);
        float4 ta = tab[(size_t)l * NTAB + j0];
        float4 tb = tab[(size_t)l * NTAB + j1];
        float f0 = fmaf(fr, tb.x - ta.x, ta.x);
        float f1 = fmaf(fr, tb.y - ta.y, ta.y);
        float f2 = fmaf(fr, tb.z - ta.z, ta.z);
        // residual + ln2
        float y0 = hn0 + f0 + b2v[l*3+0];
        float y1 = hn1 + f1 + b2v[l*3+1];
        float y2 = hn2 + f2 + b2v[l*3+2];
        float mu2 = (y0 + y1 + y2) * (1.f/3.f);
        float e0 = y0 - mu2, e1 = y1 - mu2, e2 = y2 - mu2;
        float var2 = (e0*e0 + e1*e1 + e2*e2) * (1.f/3.f);
        float inv2 = 1.0f / sqrtf(var2 + EPS);
        h0 = fmaf(e0 * inv2, ln2_g[l*3+0], ln2_b[l*3+0]);
        h1 = fmaf(e1 * inv2, ln2_g[l*3+1], ln2_b[l*3+1]);
        h2 = fmaf(e2 * inv2, ln2_g[l*3+2], ln2_b[l*3+2]);
    }
    float* hp = h + (size_t)b * 3072 + flat;
    hp[0] = h0; hp[1] = h1; hp[2] = h2;
}

__global__ void head_kernel(const float* __restrict__ h,
                            const float* __restrict__ mlp_W,
                            const float* __restrict__ mlp_b,
                            float* __restrict__ out) {
    int b = blockIdx.x, tid = threadIdx.x;
    float hh[12];
#pragma unroll
    for (int m = 0; m < 12; ++m) hh[m] = h[(size_t)b * 3072 + tid + m * 256];
    float p[10];
#pragma unroll
    for (int j = 0; j < 10; ++j) {
        const float* wj = mlp_W + (size_t)j * 3072;
        float s = 0.f;
#pragma unroll
        for (int m = 0; m < 12; ++m) s = fmaf(hh[m], wj[tid + m * 256], s);
#pragma unroll
        for (int d = 32; d >= 1; d >>= 1) s += __shfl_down(s, d);
        p[j] = s;
    }
    __shared__ float red[10][4];
    int wave = tid >> 6, lane = tid & 63;
    if (lane == 0) {
#pragma unroll
        for (int j = 0; j < 10; ++j) red[j][wave] = p[j];
    }
    __syncthreads();
    if (tid < 10)
        out[b * 10 + tid] = red[tid][0] + red[tid][1] + red[tid][2] + red[tid][3] + mlp_b[tid];
}

extern "C" void kernel_launch(void* const* d_in, const int* in_sizes, int n_in,
                              void* d_out, int out_size, void* d_ws, size_t ws_size,
                              hipStream_t stream) {
    const float* x      = (const float*)d_in[0];
    const float* conv_w = (const float*)d_in[1];
    const float* conv_b = (const float*)d_in[2];
    const float* Wqkv   = (const float*)d_in[3];
    const float* bqkv   = (const float*)d_in[4];
    const float* Wo     = (const float*)d_in[5];
    const float* bo     = (const float*)d_in[6];
    const float* W1     = (const float*)d_in[7];
    const float* b1     = (const float*)d_in[8];
    const float* W2     = (const float*)d_in[9];
    const float* b2     = (const float*)d_in[10];
    const float* ln1_g  = (const float*)d_in[11];
    const float* ln1_b  = (const float*)d_in[12];
    const float* ln2_g  = (const float*)d_in[13];
    const float* ln2_b  = (const float*)d_in[14];
    const float* mlp_W  = (const float*)d_in[15];
    const float* mlp_b  = (const float*)d_in[16];
    float* out = (float*)d_out;

    float*  h   = (float*)d_ws;                        // 98304 floats (393216 B)
    float4* tab = (float4*)((char*)d_ws + 393216);     // 6*NTAB float4

    hipLaunchKernelGGL(tab_kernel, dim3(LAYERS * (NTAB / 16)), dim3(256), 0, stream,
                       W1, b1, W2, ln1_g, ln1_b, tab);
    hipLaunchKernelGGL(fused6_kernel, dim3(512), dim3(64), 0, stream,
                       x, conv_w, conv_b, Wqkv, bqkv, Wo, bo,
                       ln1_g, ln1_b, b2, ln2_g, ln2_b, tab, h);
    hipLaunchKernelGGL(head_kernel, dim3(32), dim3(256), 0, stream, h, mlp_W, mlp_b, out);
}

// Round 6
// 40.372 us; speedup vs baseline: 34.2485x; 1.0545x over previous
//
#include <hip/hip_runtime.h>
#include <math.h>

#define EPS 1e-5f
#define LAYERS 6
#define FDIM 2048
#define NTAB 512

// h layout: [b][3072] flat, element (s,n,e) at b*3072 + s*96 + n*3 + e

__device__ __forceinline__ float gelu_as(float t) {
    // A&S 7.1.26 erf, branchless: gl = relu(t) - 0.5*|t|*poly*exp(-t^2/2)
    float e  = __expf(-0.5f * t * t);
    float at = fabsf(t);
    float wr = __builtin_amdgcn_rcpf(fmaf(0.23164194f, at, 1.0f));
    float poly = fmaf(fmaf(fmaf(fmaf(1.061405429f, wr, -1.453152027f),
                                wr, 1.421413741f),
                           wr, -0.284496736f),
                      wr, 0.254829592f) * wr;
    return fmaf(-0.5f * at, poly * e, fmaxf(t, 0.f));
}

// tab[l][j] = MLP_acc( hn(theta_j) ), hn = ln1_g * z(theta_j) + ln1_b,
// z on the radius-sqrt(3) circle in the plane z0+z1+z2=0.
// Slot j <-> diamond coordinate d = j*(4/NTAB).
// One table entry per block; 256 threads split the 2048 hidden units.
__global__ __launch_bounds__(256) void tab_kernel(
        const float* __restrict__ W1, const float* __restrict__ b1,
        const float* __restrict__ W2,
        const float* __restrict__ ln1_g, const float* __restrict__ ln1_b,
        float4* __restrict__ tab) {
    int l = blockIdx.x >> 9;           // NTAB = 512 entries per layer
    int j = blockIdx.x & (NTAB - 1);
    int tid = threadIdx.x;
    int wv = tid >> 6, lane = tid & 63;

    float d = (float)j * (4.0f / NTAB);
    float cn = (d <= 2.0f) ? 1.0f - d : d - 3.0f;
    float asn = 1.0f - fabsf(cn);
    float sn = (d <= 2.0f) ? asn : -asn;
    float inv = 1.0f / sqrtf(cn * cn + sn * sn);
    float c = cn * inv, s = sn * inv;
    float z0 = fmaf(1.2247449f, c, 0.70710678f * s);
    float z1 = fmaf(-1.2247449f, c, 0.70710678f * s);
    float z2 = -1.4142136f * s;
    float hx0 = fmaf(ln1_g[l*3+0], z0, ln1_b[l*3+0]);
    float hx1 = fmaf(ln1_g[l*3+1], z1, ln1_b[l*3+1]);
    float hx2 = fmaf(ln1_g[l*3+2], z2, ln1_b[l*3+2]);

    const float* w1p = W1 + (size_t)l * FDIM * 3;
    const float* b1p = b1 + (size_t)l * FDIM;
    const float* w2p = W2 + (size_t)l * 3 * FDIM;

    float a0 = 0.f, a1 = 0.f, a2 = 0.f;
#pragma unroll
    for (int i = 0; i < 8; ++i) {
        int k = i * 256 + tid;
        float t = fmaf(w1p[k*3+0], hx0,
                  fmaf(w1p[k*3+1], hx1,
                  fmaf(w1p[k*3+2], hx2, b1p[k])));
        float gl = gelu_as(t);
        a0 = fmaf(gl, w2p[k],          a0);
        a1 = fmaf(gl, w2p[FDIM + k],   a1);
        a2 = fmaf(gl, w2p[2*FDIM + k], a2);
    }
#pragma unroll
    for (int m = 1; m < 64; m <<= 1) {
        a0 += __shfl_xor(a0, m);
        a1 += __shfl_xor(a1, m);
        a2 += __shfl_xor(a2, m);
    }
    __shared__ float red[4][3];
    if (lane == 0) { red[wv][0] = a0; red[wv][1] = a1; red[wv][2] = a2; }
    __syncthreads();
    if (tid == 0) {
        tab[(size_t)l * NTAB + j] = make_float4(
            red[0][0] + red[1][0] + red[2][0] + red[3][0],
            red[0][1] + red[1][1] + red[2][1] + red[3][1],
            red[0][2] + red[1][2] + red[2][2] + red[3][2], 0.f);
    }
}

// conv + all 6 layers fused. Block = one wave: (batch b, pair of n's) x 32 s.
// conv's three 1024-dot scalars are recomputed per block (cheap); h stays in
// registers across all layers; attention mixes only within the wave's 32 s.
__global__ __launch_bounds__(64) void fused6_kernel(
        const float* __restrict__ x,
        const float* __restrict__ conv_w, const float* __restrict__ conv_b,
        const float* __restrict__ Wqkv, const float* __restrict__ bqkv,
        const float* __restrict__ Wo,   const float* __restrict__ bo,
        const float* __restrict__ ln1_g, const float* __restrict__ ln1_b,
        const float* __restrict__ b2v,
        const float* __restrict__ ln2_g, const float* __restrict__ ln2_b,
        const float4* __restrict__ tab,
        float* __restrict__ h) {
    int b = blockIdx.x >> 4, ngrp = blockIdx.x & 15;
    int tid = threadIdx.x;
    int s = tid & 31, nl = tid >> 5;   // nl in {0,1}
    int n = ngrp * 2 + nl;
    __shared__ float kbuf[2][3][32], vbuf[2][3][32];

    // in-block conv: c[ch] = dot(x[b,ch,:,:], conv_w[ch]) + conv_b[ch]
    const float4* xb4 = (const float4*)(x + (size_t)b * 3072);
    const float4* cw4 = (const float4*)conv_w;
    float cs0 = 0.f, cs1 = 0.f, cs2 = 0.f;
#pragma unroll
    for (int i = 0; i < 4; ++i) {
        int f0 = i * 64 + tid;
        float4 xv = xb4[f0], wv = cw4[f0];
        cs0 = fmaf(xv.x, wv.x, fmaf(xv.y, wv.y, fmaf(xv.z, wv.z, fmaf(xv.w, wv.w, cs0))));
        float4 xv1 = xb4[f0 + 256], wv1 = cw4[f0 + 256];
        cs1 = fmaf(xv1.x, wv1.x, fmaf(xv1.y, wv1.y, fmaf(xv1.z, wv1.z, fmaf(xv1.w, wv1.w, cs1))));
        float4 xv2 = xb4[f0 + 512], wv2 = cw4[f0 + 512];
        cs2 = fmaf(xv2.x, wv2.x, fmaf(xv2.y, wv2.y, fmaf(xv2.z, wv2.z, fmaf(xv2.w, wv2.w, cs2))));
    }
#pragma unroll
    for (int m = 1; m < 64; m <<= 1) {
        cs0 += __shfl_xor(cs0, m);
        cs1 += __shfl_xor(cs1, m);
        cs2 += __shfl_xor(cs2, m);
    }
    float c0 = cs0 + conv_b[0], c1 = cs1 + conv_b[1], c2 = cs2 + conv_b[2];

    int flat = s * 96 + n * 3;
    const float* xb = x + (size_t)b * 3072 + flat;
    float h0 = xb[0] + ((flat     < 1024) ? c0 : (flat     < 2048 ? c1 : c2));
    float h1 = xb[1] + ((flat + 1 < 1024) ? c0 : (flat + 1 < 2048 ? c1 : c2));
    float h2 = xb[2] + ((flat + 2 < 1024) ? c0 : (flat + 2 < 2048 ? c1 : c2));

    for (int l = 0; l < LAYERS; ++l) {
        const float* wq = Wqkv + l * 27;
        const float* bq = bqkv + l * 9;
        float q[3], kk[3], vv[3];
#pragma unroll
        for (int f = 0; f < 3; ++f) {
            q[f]  = fmaf(wq[f*3+0], h0, fmaf(wq[f*3+1], h1, fmaf(wq[f*3+2], h2, bq[f])));
            kk[f] = fmaf(wq[9+f*3+0], h0, fmaf(wq[9+f*3+1], h1, fmaf(wq[9+f*3+2], h2, bq[3+f])));
            vv[f] = fmaf(wq[18+f*3+0], h0, fmaf(wq[18+f*3+1], h1, fmaf(wq[18+f*3+2], h2, bq[6+f])));
        }
        __syncthreads();   // single-wave block: near-free; orders kbuf reuse
#pragma unroll
        for (int e = 0; e < 3; ++e) { kbuf[nl][e][s] = kk[e]; vbuf[nl][e][s] = vv[e]; }
        __syncthreads();

        float oatt[3];
#pragma unroll
        for (int e = 0; e < 3; ++e) {
            float a = q[e] * 1.44269504f;   // exp2 base; no max-sub (|q*k| bounded)
            float sum = 0.f, acc = 0.f;
#pragma unroll
            for (int t = 0; t < 32; ++t) {
                float p = exp2f(a * kbuf[nl][e][t]);
                sum += p;
                acc = fmaf(p, vbuf[nl][e][t], acc);
            }
            oatt[e] = acc / sum;
        }
        const float* wo = Wo + l * 9;
        float x0 = h0 + fmaf(wo[0], oatt[0], fmaf(wo[1], oatt[1], fmaf(wo[2], oatt[2], bo[l*3+0])));
        float x1 = h1 + fmaf(wo[3], oatt[0], fmaf(wo[4], oatt[1], fmaf(wo[5], oatt[2], bo[l*3+1])));
        float x2 = h2 + fmaf(wo[6], oatt[0], fmaf(wo[7], oatt[1], fmaf(wo[8], oatt[2], bo[l*3+2])));
        // ln1 -> z (pre-gain), hn (post-gain)
        float mu = (x0 + x1 + x2) * (1.f/3.f);
        float d0 = x0 - mu, d1 = x1 - mu, d2 = x2 - mu;
        float var = (d0*d0 + d1*d1 + d2*d2) * (1.f/3.f);
        float inv = 1.0f / sqrtf(var + EPS);
        float z0 = d0 * inv, z1 = d1 * inv, z2 = d2 * inv;
        float hn0 = fmaf(z0, ln1_g[l*3+0], ln1_b[l*3+0]);
        float hn1 = fmaf(z1, ln1_g[l*3+1], ln1_b[l*3+1]);
        float hn2 = fmaf(z2, ln1_g[l*3+2], ln1_b[l*3+2]);
        // MLP via 1-D manifold table: diamond coordinate of z
        float cc = 0.40824829f * (z0 - z1);
        float ss = 0.23570226f * (z0 + z1 - 2.f * z2);
        float m  = fabsf(cc) + fabsf(ss) + 1e-30f;
        float cnn = cc * __builtin_amdgcn_rcpf(m);
        float dq = (ss >= 0.f) ? (1.f - cnn) : (3.f + cnn);
        float xq = dq * (float)(NTAB / 4);
        float fl = floorf(xq);
        float fr = xq - fl;
        int j0 = ((int)fl) & (NTAB - 1);
        int j1 = (j0 + 1) & (NTAB - 1);
        float4 ta = tab[(size_t)l * NTAB + j0];
        float4 tb = tab[(size_t)l * NTAB + j1];
        float f0 = fmaf(fr, tb.x - ta.x, ta.x);
        float f1 = fmaf(fr, tb.y - ta.y, ta.y);
        float f2 = fmaf(fr, tb.z - ta.z, ta.z);
        // residual + ln2
        float y0 = hn0 + f0 + b2v[l*3+0];
        float y1 = hn1 + f1 + b2v[l*3+1];
        float y2 = hn2 + f2 + b2v[l*3+2];
        float mu2 = (y0 + y1 + y2) * (1.f/3.f);
        float e0 = y0 - mu2, e1 = y1 - mu2, e2 = y2 - mu2;
        float var2 = (e0*e0 + e1*e1 + e2*e2) * (1.f/3.f);
        float inv2 = 1.0f / sqrtf(var2 + EPS);
        h0 = fmaf(e0 * inv2, ln2_g[l*3+0], ln2_b[l*3+0]);
        h1 = fmaf(e1 * inv2, ln2_g[l*3+1], ln2_b[l*3+1]);
        h2 = fmaf(e2 * inv2, ln2_g[l*3+2], ln2_b[l*3+2]);
    }
    float* hp = h + (size_t)b * 3072 + flat;
    hp[0] = h0; hp[1] = h1; hp[2] = h2;
}

__global__ void head_kernel(const float* __restrict__ h,
                            const float* __restrict__ mlp_W,
                            const float* __restrict__ mlp_b,
                            float* __restrict__ out) {
    int b = blockIdx.x, tid = threadIdx.x;
    float hh[12];
#pragma unroll
    for (int m = 0; m < 12; ++m) hh[m] = h[(size_t)b * 3072 + tid + m * 256];
    float p[10];
#pragma unroll
    for (int j = 0; j < 10; ++j) {
        const float* wj = mlp_W + (size_t)j * 3072;
        float s = 0.f;
#pragma unroll
        for (int m = 0; m < 12; ++m) s = fmaf(hh[m], wj[tid + m * 256], s);
#pragma unroll
        for (int d = 32; d >= 1; d >>= 1) s += __shfl_down(s, d);
        p[j] = s;
    }
    __shared__ float red[10][4];
    int wave = tid >> 6, lane = tid & 63;
    if (lane == 0) {
#pragma unroll
        for (int j = 0; j < 10; ++j) red[j][wave] = p[j];
    }
    __syncthreads();
    if (tid < 10)
        out[b * 10 + tid] = red[tid][0] + red[tid][1] + red[tid][2] + red[tid][3] + mlp_b[tid];
}

extern "C" void kernel_launch(void* const* d_in, const int* in_sizes, int n_in,
                              void* d_out, int out_size, void* d_ws, size_t ws_size,
                              hipStream_t stream) {
    const float* x      = (const float*)d_in[0];
    const float* conv_w = (const float*)d_in[1];
    const float* conv_b = (const float*)d_in[2];
    const float* Wqkv   = (const float*)d_in[3];
    const float* bqkv   = (const float*)d_in[4];
    const float* Wo     = (const float*)d_in[5];
    const float* bo     = (const float*)d_in[6];
    const float* W1     = (const float*)d_in[7];
    const float* b1     = (const float*)d_in[8];
    const float* W2     = (const float*)d_in[9];
    const float* b2     = (const float*)d_in[10];
    const float* ln1_g  = (const float*)d_in[11];
    const float* ln1_b  = (const float*)d_in[12];
    const float* ln2_g  = (const float*)d_in[13];
    const float* ln2_b  = (const float*)d_in[14];
    const float* mlp_W  = (const float*)d_in[15];
    const float* mlp_b  = (const float*)d_in[16];
    float* out = (float*)d_out;

    float*  h   = (float*)d_ws;                        // 98304 floats (393216 B)
    float4* tab = (float4*)((char*)d_ws + 393216);     // 6*NTAB float4

    hipLaunchKernelGGL(tab_kernel, dim3(LAYERS * NTAB), dim3(256), 0, stream,
                       W1, b1, W2, ln1_g, ln1_b, tab);
    hipLaunchKernelGGL(fused6_kernel, dim3(512), dim3(64), 0, stream,
                       x, conv_w, conv_b, Wqkv, bqkv, Wo, bo,
                       ln1_g, ln1_b, b2, ln2_g, ln2_b, tab, h);
    hipLaunchKernelGGL(head_kernel, dim3(32), dim3(256), 0, stream, h, mlp_W, mlp_b, out);
}